// Round 1
// baseline (99.901 us; speedup 1.0000x reference)
//
#include <hip/hip_runtime.h>
#include <hip/hip_bf16.h>

typedef __attribute__((ext_vector_type(4))) float f32x4;
typedef __attribute__((ext_vector_type(8))) _Float16 f16x8;
typedef __attribute__((ext_vector_type(4))) int i32x4;

#define NB 32
#define MM 1024
#define DD 128
#define BKV 64

static constexpr size_t ARR = (size_t)NB * MM * DD;  // 4,194,304 elems per f16 array

// ws layout (f16): Ah @0, Bh @ARR, ATh @2*ARR, BTh @3*ARR
// Row-major arrays Xh[b][r][128]: 16B chunk c of row r stored at in-row byte (c*16) ^ ((r&7)<<4)
// Transposed XTh[b][d][1024]: within each 64-i (128B) window, chunk c at (c*16) ^ ((d&7)<<4)

__device__ __forceinline__ float fexp2(float x) { return __builtin_amdgcn_exp2f(x); }

__global__ __launch_bounds__(256) void prep_kernel(const float* __restrict__ A,
                                                   const float* __restrict__ B,
                                                   _Float16* __restrict__ ws) {
  const int rt = blockIdx.x;     // 64-row tile
  const int b  = blockIdx.y;
  const int wh = blockIdx.z;     // 0=A, 1=B
  const float* __restrict__ src = wh ? B : A;
  _Float16* __restrict__ Xh  = ws + (size_t)wh * ARR;
  _Float16* __restrict__ XTh = ws + 2 * ARR + (size_t)wh * ARR;

  __shared__ __align__(16) _Float16 tile[64][130];
  const int t = threadIdx.x;

  // phase 1: f32 -> f16, write row-major swizzled, stash in LDS
#pragma unroll
  for (int it = 0; it < 4; ++it) {
    int id  = it * 256 + t;          // 0..1023 (16B chunks)
    int row = id >> 4;               // 0..63
    int ch  = id & 15;
    int grow = rt * 64 + row;
    const float* p = src + ((size_t)(b * MM + grow) * DD + ch * 8);
    float4 x0 = *(const float4*)p;
    float4 x1 = *(const float4*)(p + 4);
    f16x8 h;
    h[0] = (_Float16)x0.x; h[1] = (_Float16)x0.y; h[2] = (_Float16)x0.z; h[3] = (_Float16)x0.w;
    h[4] = (_Float16)x1.x; h[5] = (_Float16)x1.y; h[6] = (_Float16)x1.z; h[7] = (_Float16)x1.w;
    char* dst = (char*)Xh + (((size_t)(b * MM + grow)) << 8) + ((ch << 4) ^ ((row & 7) << 4));
    *(f16x8*)dst = h;
#pragma unroll
    for (int j = 0; j < 8; ++j) tile[row][ch * 8 + j] = h[j];
  }
  __syncthreads();

  // phase 2: transposed swizzled write
#pragma unroll
  for (int it = 0; it < 4; ++it) {
    int id = it * 256 + t;           // 0..1023
    int d  = id >> 3;                // 0..127
    int ch = id & 7;                 // 8-i chunk within this tile's 64-i window
    f16x8 h;
#pragma unroll
    for (int j = 0; j < 8; ++j) h[j] = tile[ch * 8 + j][d];
    char* dst = (char*)XTh + (((size_t)(b * DD + d)) << 11) + (rt << 7)
              + ((ch << 4) ^ ((d & 7) << 4));
    *(f16x8*)dst = h;
  }
}

__global__ __launch_bounds__(256) void attn_kernel(const _Float16* __restrict__ ws,
                                                   float* __restrict__ out) {
  const int qt  = blockIdx.x;   // 0..15 (64-row Q tile)
  const int b   = blockIdx.y;   // 0..31
  const int dir = blockIdx.z;   // 0: beta (Q=A,K=V=B), 1: alpha (Q=B,K=V=A)

  const _Float16* __restrict__ Qh  = ws + (dir ? ARR : 0);
  const _Float16* __restrict__ Kh  = ws + (dir ? 0 : ARR);
  const _Float16* __restrict__ VTh = ws + 2 * ARR + (dir ? 0 : ARR);
  float* __restrict__ outp = out + (size_t)dir * ARR;

  __shared__ __align__(16) _Float16 sK[64 * 128];    // 16 KB, swizzled rows [kv][d]
  __shared__ __align__(16) _Float16 sVT[128 * 64];   // 16 KB, swizzled rows [d][kv]
  __shared__ __align__(16) _Float16 sP[4][16 * 64];  // per-wave P, 2 KB each

  const int tid  = threadIdx.x;
  const int w    = tid >> 6;
  const int lane = tid & 63;
  const int lrow = lane & 15;   // MFMA A-row / B-col / C-col
  const int lgrp = lane >> 4;   // k-group

  // Q fragments: A[row=lrow][k = kc*32 + lgrp*8 + 0..7]
  const int qrow = qt * 64 + w * 16 + lrow;
  f16x8 qfrag[4];
  {
    const char* qbase = (const char*)Qh + (((size_t)(b * MM + qrow)) << 8);
    const int swz = (lrow & 7) << 4;
#pragma unroll
    for (int kc = 0; kc < 4; ++kc)
      qfrag[kc] = *(const f16x8*)(qbase + ((kc * 64 + lgrp * 16) ^ swz));
  }

  f32x4 oacc[8];
#pragma unroll
  for (int i = 0; i < 8; ++i) oacc[i] = (f32x4)0.0f;
  float mrun[4], lrun[4];
#pragma unroll
  for (int r = 0; r < 4; ++r) { mrun[r] = -1e30f; lrun[r] = 0.0f; }

  for (int kv0 = 0; kv0 < MM; kv0 += BKV) {
    // ---- stage K (contiguous 16KB) and VT (128B row windows) into LDS
    {
      const i32x4* gK = (const i32x4*)((const char*)Kh + (((size_t)(b * MM + kv0)) << 8));
      i32x4* sKv = (i32x4*)sK;
#pragma unroll
      for (int it = 0; it < 4; ++it) {
        int c = it * 256 + tid;
        sKv[c] = gK[c];
      }
      i32x4* sVv = (i32x4*)sVT;
      const char* gVb = (const char*)VTh + (((size_t)(b * DD)) << 11) + ((size_t)kv0 << 1);
#pragma unroll
      for (int it = 0; it < 4; ++it) {
        int c = it * 256 + tid;
        int drow = c >> 3, inb = (c & 7) << 4;
        sVv[c] = *(const i32x4*)(gVb + ((size_t)drow << 11) + inb);
      }
    }
    __syncthreads();

    // ---- S = Q K^T  (wave tile 16x64), fp32 acc
    f32x4 sacc[4];
#pragma unroll
    for (int nt = 0; nt < 4; ++nt) sacc[nt] = (f32x4)0.0f;
#pragma unroll
    for (int nt = 0; nt < 4; ++nt) {
      const int kvloc = nt * 16 + lrow;
      const char* kr = (const char*)sK + kvloc * 256;
      const int swz = (kvloc & 7) << 4;
#pragma unroll
      for (int kc = 0; kc < 4; ++kc) {
        f16x8 kf = *(const f16x8*)(kr + ((kc * 64 + lgrp * 16) ^ swz));
        sacc[nt] = __builtin_amdgcn_mfma_f32_16x16x32_f16(qfrag[kc], kf, sacc[nt], 0, 0, 0);
      }
    }

    // ---- online softmax; lane's rows are lgrp*4 + r, col = lrow (+16*nt)
    float scale[4], psum[4];
#pragma unroll
    for (int r = 0; r < 4; ++r) {
      float mx = fmaxf(fmaxf(sacc[0][r], sacc[1][r]), fmaxf(sacc[2][r], sacc[3][r]));
      mx = fmaxf(mx, __shfl_xor(mx, 1));
      mx = fmaxf(mx, __shfl_xor(mx, 2));
      mx = fmaxf(mx, __shfl_xor(mx, 4));
      mx = fmaxf(mx, __shfl_xor(mx, 8));
      float mnew = fmaxf(mrun[r], mx);
      scale[r] = fexp2((mrun[r] - mnew) * 1.44269504089f);
      mrun[r] = mnew;
      psum[r] = 0.0f;
    }
    {
      _Float16* pw = sP[w];
#pragma unroll
      for (int r = 0; r < 4; ++r) {
        const int prow = lgrp * 4 + r;
        char* pr = (char*)pw + prow * 128;
        const int swz = (prow & 7) << 4;
#pragma unroll
        for (int nt = 0; nt < 4; ++nt) {
          float p = fexp2((sacc[nt][r] - mrun[r]) * 1.44269504089f);
          psum[r] += p;
          *(_Float16*)(pr + (((nt * 16 + lrow) * 2) ^ swz)) = (_Float16)p;
        }
      }
    }
#pragma unroll
    for (int r = 0; r < 4; ++r) {
      float s = psum[r];
      s += __shfl_xor(s, 1);
      s += __shfl_xor(s, 2);
      s += __shfl_xor(s, 4);
      s += __shfl_xor(s, 8);
      lrun[r] = lrun[r] * scale[r] + s;
    }
#pragma unroll
    for (int dt = 0; dt < 8; ++dt)
#pragma unroll
      for (int r = 0; r < 4; ++r) oacc[dt][r] *= scale[r];

    // ---- PV: O += P (16x64) * V (64x128)
    {
      const _Float16* pw = sP[w];
      f16x8 pfrag[2];
      {
        const char* pr = (const char*)pw + lrow * 128;
        const int swz = (lrow & 7) << 4;
        pfrag[0] = *(const f16x8*)(pr + ((lgrp * 16) ^ swz));
        pfrag[1] = *(const f16x8*)(pr + ((64 + lgrp * 16) ^ swz));
      }
#pragma unroll
      for (int dt = 0; dt < 8; ++dt) {
        const int drow = dt * 16 + lrow;
        const char* vr = (const char*)sVT + drow * 128;
        const int swz = (drow & 7) << 4;
#pragma unroll
        for (int kc2 = 0; kc2 < 2; ++kc2) {
          f16x8 vf = *(const f16x8*)(vr + ((kc2 * 64 + lgrp * 16) ^ swz));
          oacc[dt] = __builtin_amdgcn_mfma_f32_16x16x32_f16(pfrag[kc2], vf, oacc[dt], 0, 0, 0);
        }
      }
    }
    __syncthreads();
  }

  // ---- epilogue: normalize and store fp32
  const int orow = qt * 64 + w * 16 + lgrp * 4;
#pragma unroll
  for (int r = 0; r < 4; ++r) {
    float inv = __builtin_amdgcn_rcpf(lrun[r]);
    float* op = outp + ((size_t)(b * MM + orow + r)) * DD + lrow;
#pragma unroll
    for (int dt = 0; dt < 8; ++dt) op[dt * 16] = oacc[dt][r] * inv;
  }
}

extern "C" void kernel_launch(void* const* d_in, const int* in_sizes, int n_in,
                              void* d_out, int out_size, void* d_ws, size_t ws_size,
                              hipStream_t stream) {
  const float* A = (const float*)d_in[0];
  const float* B = (const float*)d_in[1];
  float* out = (float*)d_out;
  if (ws_size < 4 * ARR * sizeof(_Float16)) return;  // need 33.6 MB scratch
  _Float16* ws = (_Float16*)d_ws;

  dim3 blk(256, 1, 1);
  dim3 g1(16, 32, 2);
  prep_kernel<<<g1, blk, 0, stream>>>(A, B, ws);
  dim3 g2(16, 32, 2);
  attn_kernel<<<g2, blk, 0, stream>>>(ws, out);
}

// Round 3
// 62.313 us; speedup vs baseline: 1.6032x; 1.6032x over previous
//
#include <hip/hip_runtime.h>
#include <hip/hip_bf16.h>
#include <stdint.h>

typedef __attribute__((ext_vector_type(4))) float f32x4;
typedef __attribute__((ext_vector_type(8))) _Float16 f16x8;
typedef __attribute__((ext_vector_type(2))) __fp16 fp16x2;

#define NB 32
#define MM 1024
#define DD 128
#define BKV 64
#define NTILE (MM / BKV)
#define LOG2E 1.44269504089f
#define RTHR 6.0f

static constexpr size_t ARR = (size_t)NB * MM * DD;  // elems per array

// ws layout (f16): Ah @0, Bh @ARR, ATh @2*ARR, BTh @3*ARR
// Row-major Xh[b][r][128]: 16B chunk c of row r at in-row byte (c*16) ^ ((r&7)<<4)
// Transposed XTh[b][d][1024]: per 64-kv (128B) window, chunk c at (c*16) ^ ((d&7)<<4),
//   and kv POSITIONS within each window are sigma_V-permuted (see prep phase 2).

__device__ __forceinline__ float fexp2(float x) { return __builtin_amdgcn_exp2f(x); }

__device__ __forceinline__ void gl16(const void* g, void* l) {
  __builtin_amdgcn_global_load_lds((const __attribute__((address_space(1))) void*)g,
                                   (__attribute__((address_space(3))) void*)l, 16, 0, 0);
}

__global__ __launch_bounds__(256) void prep_kernel(const float* __restrict__ A,
                                                   const float* __restrict__ B,
                                                   _Float16* __restrict__ ws) {
  const int rt = blockIdx.x;     // 64-row tile
  const int b  = blockIdx.y;
  const int wh = blockIdx.z;     // 0=A, 1=B
  const float* __restrict__ src = wh ? B : A;
  _Float16* __restrict__ Xh  = ws + (size_t)wh * ARR;
  _Float16* __restrict__ XTh = ws + 2 * ARR + (size_t)wh * ARR;

  __shared__ __align__(16) _Float16 tile[64][130];
  const int t = threadIdx.x;

  // phase 1: f32 -> f16, row-major swizzled write + LDS stash
#pragma unroll
  for (int it = 0; it < 4; ++it) {
    int id  = it * 256 + t;          // 0..1023 (16B chunks)
    int row = id >> 4;               // 0..63
    int ch  = id & 15;
    int grow = rt * 64 + row;
    const float* p = src + ((size_t)(b * MM + grow) * DD + ch * 8);
    float4 x0 = *(const float4*)p;
    float4 x1 = *(const float4*)(p + 4);
    f16x8 h;
    h[0] = (_Float16)x0.x; h[1] = (_Float16)x0.y; h[2] = (_Float16)x0.z; h[3] = (_Float16)x0.w;
    h[4] = (_Float16)x1.x; h[5] = (_Float16)x1.y; h[6] = (_Float16)x1.z; h[7] = (_Float16)x1.w;
    char* dst = (char*)Xh + (((size_t)(b * MM + grow)) << 8) + ((ch << 4) ^ ((row & 7) << 4));
    *(f16x8*)dst = h;
#pragma unroll
    for (int j = 0; j < 8; ++j) tile[row][ch * 8 + j] = h[j];
  }
  __syncthreads();

  // phase 2: transposed, sigma_V-permuted, swizzled write.
  // sigma_V(i): out5=i5, out4=i2, out3=i4, out2=i3, out1:0=i1:0
#pragma unroll
  for (int it = 0; it < 4; ++it) {
    int id = it * 256 + t;           // 0..1023
    int d  = id >> 3;                // 0..127
    int ch = id & 7;                 // 16B chunk within this tile's 64-kv window
    f16x8 h;
#pragma unroll
    for (int j = 0; j < 8; ++j) {
      int i = ch * 8 + j;
      int s = (i & 0x23) | ((i & 4) << 2) | ((i & 24) >> 1);
      h[j] = tile[s][d];
    }
    char* dst = (char*)XTh + (((size_t)(b * DD + d)) << 11) + (rt << 7)
              + ((ch << 4) ^ ((d & 7) << 4));
    *(f16x8*)dst = h;
  }
}

__global__ __launch_bounds__(256, 2) void attn_kernel(const _Float16* __restrict__ ws,
                                                      float* __restrict__ out) {
  // XCD-aware decomposition: blocks with same (b,dir) land on same XCD (g%8 fixed)
  const int g   = blockIdx.x;           // 0..511
  const int x   = g & 7;
  const int t2  = g >> 3;
  const int qt  = t2 & 7;               // 0..7 (128-row Q tile)
  const int p   = ((t2 >> 3) << 3) | x; // 0..63 = b + 32*dir
  const int b   = p & 31;
  const int dir = p >> 5;

  const _Float16* __restrict__ Qh  = ws + (dir ? ARR : 0);
  const _Float16* __restrict__ Kh  = ws + (dir ? 0 : ARR);
  const _Float16* __restrict__ VTh = ws + 2 * ARR + (dir ? 0 : ARR);
  float* __restrict__ outp = out + (size_t)dir * ARR;

  // double buffer: [buf][ K tile 16KB | VT tile 16KB ]
  __shared__ __align__(16) char sbuf[2][32768];

  const int tid  = threadIdx.x;
  const int w    = tid >> 6;
  const int lane = tid & 63;
  const int lrow = lane & 15;
  const int lgrp = lane >> 4;

  const int q0 = qt * 128 + w * 32 + lrow;   // qblk0; qblk1 = q0+16

  // ---- Q B-fragments (both q-blocks), loaded once from global
  f16x8 qf[2][4];
  {
    const int swz = (lrow & 7) << 4;
#pragma unroll
    for (int qb = 0; qb < 2; ++qb) {
      const char* qbase = (const char*)Qh + (((size_t)(b * MM + q0 + qb * 16)) << 8);
#pragma unroll
      for (int kc = 0; kc < 4; ++kc)
        qf[qb][kc] = *(const f16x8*)(qbase + ((kc * 64 + lgrp * 16) ^ swz));
    }
  }

  // ---- per-lane LDS byte-offset bases (swizzle folded; kc parity split)
  const int pl  = (lgrp * 16) ^ ((lrow & 3) << 4);
  const int lb6 = (lrow & 4) << 4;           // 0 or 64
  const int kE = lrow * 256 + pl + lb6;          // K reads, kc even
  const int kO = lrow * 256 + pl + (64 - lb6);   // K reads, kc odd
  const int vE = 16384 + lrow * 128 + pl + lb6;          // VT reads, kc2=0
  const int vO = 16384 + lrow * 128 + pl + (64 - lb6);   // VT reads, kc2=1

  // ---- staging source bases (per-thread)
  const char* ksrc = (const char*)Kh + (((size_t)b * MM) << 8) + (size_t)tid * 16;
  const char* vsrc = (const char*)VTh + (((size_t)b * DD) << 11)
                   + ((size_t)(tid >> 3) << 11) + (size_t)(tid & 7) * 16;

  f32x4 oacc[2][8];
#pragma unroll
  for (int qb = 0; qb < 2; ++qb)
#pragma unroll
    for (int dt = 0; dt < 8; ++dt) oacc[qb][dt] = (f32x4)0.0f;
  float mrun[2] = {-1e30f, -1e30f};
  float lrun[2] = {0.0f, 0.0f};

  // prologue: stage tile 0 into buf 0
  {
    char* sb = sbuf[0];
#pragma unroll
    for (int it = 0; it < 4; ++it)
      gl16(ksrc + it * 4096, sb + it * 4096 + tid * 16);
#pragma unroll
    for (int it = 0; it < 4; ++it)
      gl16(vsrc + it * 65536, sb + 16384 + it * 4096 + tid * 16);
  }
  asm volatile("s_waitcnt vmcnt(0)" ::: "memory");
  __syncthreads();

#pragma unroll 1
  for (int t = 0; t < NTILE; ++t) {
    const char* base = sbuf[t & 1];

    // issue next tile's staging early (hidden under compute)
    if (t + 1 < NTILE) {
      char* sb = sbuf[(t + 1) & 1];
      const char* kp = ksrc + (size_t)(t + 1) * 16384;
      const char* vp = vsrc + (size_t)(t + 1) * 128;
#pragma unroll
      for (int it = 0; it < 4; ++it)
        gl16(kp + it * 4096, sb + it * 4096 + tid * 16);
#pragma unroll
      for (int it = 0; it < 4; ++it)
        gl16(vp + it * 65536, sb + 16384 + it * 4096 + tid * 16);
    }

    // ---- S^T = mfma(K, Q): rows kv (lgrp*4+r +16nt), cols q (lrow)
    f32x4 sc[2][4];
#pragma unroll
    for (int qb = 0; qb < 2; ++qb)
#pragma unroll
      for (int nt = 0; nt < 4; ++nt) sc[qb][nt] = (f32x4)0.0f;
#pragma unroll
    for (int nt = 0; nt < 4; ++nt) {
#pragma unroll
      for (int kc = 0; kc < 4; ++kc) {
        const int off = ((kc & 1) ? kO + (kc - 1) * 64 : kE + kc * 64) + nt * 4096;
        f16x8 kf = *(const f16x8*)(base + off);
        sc[0][nt] = __builtin_amdgcn_mfma_f32_16x16x32_f16(kf, qf[0][kc], sc[0][nt], 0, 0, 0);
        sc[1][nt] = __builtin_amdgcn_mfma_f32_16x16x32_f16(kf, qf[1][kc], sc[1][nt], 0, 0, 0);
      }
    }

    // ---- online softmax (column-local), defer-max rescale
    float mx[2];
#pragma unroll
    for (int qb = 0; qb < 2; ++qb) {
      float m0 = fmaxf(fmaxf(sc[qb][0][0], sc[qb][0][1]), fmaxf(sc[qb][0][2], sc[qb][0][3]));
      float m1 = fmaxf(fmaxf(sc[qb][1][0], sc[qb][1][1]), fmaxf(sc[qb][1][2], sc[qb][1][3]));
      float m2 = fmaxf(fmaxf(sc[qb][2][0], sc[qb][2][1]), fmaxf(sc[qb][2][2], sc[qb][2][3]));
      float m3 = fmaxf(fmaxf(sc[qb][3][0], sc[qb][3][1]), fmaxf(sc[qb][3][2], sc[qb][3][3]));
      float m = fmaxf(fmaxf(m0, m1), fmaxf(m2, m3));
      m = fmaxf(m, __shfl_xor(m, 16));
      m = fmaxf(m, __shfl_xor(m, 32));
      mx[qb] = m;
    }
    bool need = (mx[0] > mrun[0] + RTHR) || (mx[1] > mrun[1] + RTHR);
    if (__any(need)) {
#pragma unroll
      for (int qb = 0; qb < 2; ++qb) {
        float mnew = fmaxf(mrun[qb], mx[qb]);
        float scale = fexp2((mrun[qb] - mnew) * LOG2E);
        lrun[qb] *= scale;
#pragma unroll
        for (int dt = 0; dt < 8; ++dt) oacc[qb][dt] *= scale;
        mrun[qb] = mnew;
      }
    }

    // ---- P = exp(S - m), pack to f16 B-fragments in-register (sigma_V aligned)
    f16x8 pf[2][2];
#pragma unroll
    for (int qb = 0; qb < 2; ++qb) {
      union { fp16x2 h[8]; f16x8 v[2]; } u;
      float ps = 0.0f;
      const float mr = mrun[qb];
#pragma unroll
      for (int nt = 0; nt < 4; ++nt) {
        float p0 = fexp2((sc[qb][nt][0] - mr) * LOG2E);
        float p1 = fexp2((sc[qb][nt][1] - mr) * LOG2E);
        float p2 = fexp2((sc[qb][nt][2] - mr) * LOG2E);
        float p3 = fexp2((sc[qb][nt][3] - mr) * LOG2E);
        ps += (p0 + p1) + (p2 + p3);
        u.h[nt * 2 + 0] = __builtin_amdgcn_cvt_pkrtz(p0, p1);
        u.h[nt * 2 + 1] = __builtin_amdgcn_cvt_pkrtz(p2, p3);
      }
      ps += __shfl_xor(ps, 16);
      ps += __shfl_xor(ps, 32);
      lrun[qb] += ps;
      pf[qb][0] = u.v[0];
      pf[qb][1] = u.v[1];
    }

    // ---- O^T += mfma(VT, P^T): rows d (lgrp*4+r +16dt), cols q (lrow)
#pragma unroll
    for (int dt = 0; dt < 8; ++dt) {
      f16x8 v0 = *(const f16x8*)(base + vE + dt * 2048);
      f16x8 v1 = *(const f16x8*)(base + vO + dt * 2048);
      oacc[0][dt] = __builtin_amdgcn_mfma_f32_16x16x32_f16(v0, pf[0][0], oacc[0][dt], 0, 0, 0);
      oacc[0][dt] = __builtin_amdgcn_mfma_f32_16x16x32_f16(v1, pf[0][1], oacc[0][dt], 0, 0, 0);
      oacc[1][dt] = __builtin_amdgcn_mfma_f32_16x16x32_f16(v0, pf[1][0], oacc[1][dt], 0, 0, 0);
      oacc[1][dt] = __builtin_amdgcn_mfma_f32_16x16x32_f16(v1, pf[1][1], oacc[1][dt], 0, 0, 0);
    }

    asm volatile("s_waitcnt vmcnt(0)" ::: "memory");
    __syncthreads();
  }

  // ---- epilogue: normalize, store f32x4 (lane holds 4 consecutive d per dt)
#pragma unroll
  for (int qb = 0; qb < 2; ++qb) {
    float inv = __builtin_amdgcn_rcpf(lrun[qb]);
    float* op = outp + ((size_t)(b * MM + q0 + qb * 16)) * DD + lgrp * 4;
#pragma unroll
    for (int dt = 0; dt < 8; ++dt) {
      f32x4 v = oacc[qb][dt] * inv;
      *(f32x4*)(op + dt * 16) = v;
    }
  }
}

extern "C" void kernel_launch(void* const* d_in, const int* in_sizes, int n_in,
                              void* d_out, int out_size, void* d_ws, size_t ws_size,
                              hipStream_t stream) {
  const float* A = (const float*)d_in[0];
  const float* B = (const float*)d_in[1];
  float* out = (float*)d_out;
  if (ws_size < 4 * ARR * sizeof(_Float16)) return;  // need 33.6 MB scratch
  _Float16* ws = (_Float16*)d_ws;

  dim3 blk(256, 1, 1);
  dim3 g1(16, 32, 2);
  prep_kernel<<<g1, blk, 0, stream>>>(A, B, ws);
  dim3 g2(512, 1, 1);
  attn_kernel<<<g2, blk, 0, stream>>>(ws, out);
}

// Round 4
// 58.598 us; speedup vs baseline: 1.7048x; 1.0634x over previous
//
#include <hip/hip_runtime.h>
#include <hip/hip_bf16.h>
#include <stdint.h>

typedef __attribute__((ext_vector_type(4))) float f32x4;
typedef __attribute__((ext_vector_type(8))) _Float16 f16x8;
typedef __attribute__((ext_vector_type(2))) __fp16 fp16x2;

#define NB 32
#define MM 1024
#define DD 128
#define BKV 64
#define NTILE (MM / BKV)
#define LOG2E 1.44269504089f
#define RTHR 6.0f

static constexpr size_t ARR = (size_t)NB * MM * DD;  // elems per array

// ws layout (f16): Ah @0, Bh @ARR, ATh @2*ARR, BTh @3*ARR
// Row-major Xh[b][r][128]: 16B chunk c of row r at in-row byte (c*16) ^ ((r&7)<<4)
// Transposed XTh[b][d][1024]: per 64-kv (128B) window, chunk c at (c*16) ^ ((d&7)<<4),
//   and kv POSITIONS within each window are sigma_V-permuted (see prep phase 2).

__device__ __forceinline__ float fexp2(float x) { return __builtin_amdgcn_exp2f(x); }

__device__ __forceinline__ void gl16(const void* g, void* l) {
  __builtin_amdgcn_global_load_lds((const __attribute__((address_space(1))) void*)g,
                                   (__attribute__((address_space(3))) void*)l, 16, 0, 0);
}

__global__ __launch_bounds__(256) void prep_kernel(const float* __restrict__ A,
                                                   const float* __restrict__ B,
                                                   _Float16* __restrict__ ws) {
  const int rt = blockIdx.x;     // 64-row tile
  const int b  = blockIdx.y;
  const int wh = blockIdx.z;     // 0=A, 1=B
  const float* __restrict__ src = wh ? B : A;
  _Float16* __restrict__ Xh  = ws + (size_t)wh * ARR;
  _Float16* __restrict__ XTh = ws + 2 * ARR + (size_t)wh * ARR;

  __shared__ __align__(16) _Float16 tile[64][130];
  const int t = threadIdx.x;

  // phase 1: f32 -> f16, row-major swizzled write + LDS stash
#pragma unroll
  for (int it = 0; it < 4; ++it) {
    int id  = it * 256 + t;          // 0..1023 (16B chunks)
    int row = id >> 4;               // 0..63
    int ch  = id & 15;
    int grow = rt * 64 + row;
    const float* p = src + ((size_t)(b * MM + grow) * DD + ch * 8);
    float4 x0 = *(const float4*)p;
    float4 x1 = *(const float4*)(p + 4);
    f16x8 h;
    h[0] = (_Float16)x0.x; h[1] = (_Float16)x0.y; h[2] = (_Float16)x0.z; h[3] = (_Float16)x0.w;
    h[4] = (_Float16)x1.x; h[5] = (_Float16)x1.y; h[6] = (_Float16)x1.z; h[7] = (_Float16)x1.w;
    char* dst = (char*)Xh + (((size_t)(b * MM + grow)) << 8) + ((ch << 4) ^ ((row & 7) << 4));
    *(f16x8*)dst = h;
#pragma unroll
    for (int j = 0; j < 8; ++j) tile[row][ch * 8 + j] = h[j];
  }
  __syncthreads();

  // phase 2: transposed, sigma_V-permuted, swizzled write.
  // sigma_V(i): out5=i5, out4=i2, out3=i4, out2=i3, out1:0=i1:0
#pragma unroll
  for (int it = 0; it < 4; ++it) {
    int id = it * 256 + t;           // 0..1023
    int d  = id >> 3;                // 0..127
    int ch = id & 7;                 // 16B chunk within this tile's 64-kv window
    f16x8 h;
#pragma unroll
    for (int j = 0; j < 8; ++j) {
      int i = ch * 8 + j;
      int s = (i & 0x23) | ((i & 4) << 2) | ((i & 24) >> 1);
      h[j] = tile[s][d];
    }
    char* dst = (char*)XTh + (((size_t)(b * DD + d)) << 11) + (rt << 7)
              + ((ch << 4) ^ ((d & 7) << 4));
    *(f16x8*)dst = h;
  }
}

__global__ __launch_bounds__(256, 2) void attn_kernel(const _Float16* __restrict__ ws,
                                                      float* __restrict__ out) {
  // XCD-aware decomposition: blocks with same (b,dir) land on same XCD (g%8 fixed)
  const int g   = blockIdx.x;           // 0..511
  const int x   = g & 7;
  const int t2  = g >> 3;
  const int qt  = t2 & 7;               // 0..7 (128-row Q tile)
  const int p   = ((t2 >> 3) << 3) | x; // 0..63 = b + 32*dir
  const int b   = p & 31;
  const int dir = p >> 5;

  const _Float16* __restrict__ Qh  = ws + (dir ? ARR : 0);
  const _Float16* __restrict__ Kh  = ws + (dir ? 0 : ARR);
  const _Float16* __restrict__ VTh = ws + 2 * ARR + (dir ? 0 : ARR);
  float* __restrict__ outp = out + (size_t)dir * ARR;

  // double buffer: [buf][ K tile 16KB | VT tile 16KB ]
  __shared__ __align__(16) char sbuf[2][32768];

  const int tid  = threadIdx.x;
  const int w    = tid >> 6;
  const int lane = tid & 63;
  const int lrow = lane & 15;
  const int lgrp = lane >> 4;

  const int q0 = qt * 128 + w * 32 + lrow;   // qblk0; qblk1 = q0+16

  // ---- Q B-fragments (both q-blocks), loaded once from global
  f16x8 qf[2][4];
  {
    const int swz = (lrow & 7) << 4;
#pragma unroll
    for (int qb = 0; qb < 2; ++qb) {
      const char* qbase = (const char*)Qh + (((size_t)(b * MM + q0 + qb * 16)) << 8);
#pragma unroll
      for (int kc = 0; kc < 4; ++kc)
        qf[qb][kc] = *(const f16x8*)(qbase + ((kc * 64 + lgrp * 16) ^ swz));
    }
  }

  // ---- per-lane LDS byte-offset bases (swizzle folded; kc parity split)
  const int pl  = (lgrp * 16) ^ ((lrow & 3) << 4);
  const int lb6 = (lrow & 4) << 4;           // 0 or 64
  const int kE = lrow * 256 + pl + lb6;          // K reads, kc even
  const int kO = lrow * 256 + pl + (64 - lb6);   // K reads, kc odd
  const int vE = 16384 + lrow * 128 + pl + lb6;          // VT reads, kc2=0
  const int vO = 16384 + lrow * 128 + pl + (64 - lb6);   // VT reads, kc2=1

  // ---- staging source bases (per-thread)
  const char* ksrc = (const char*)Kh + (((size_t)b * MM) << 8) + (size_t)tid * 16;
  const char* vsrc = (const char*)VTh + (((size_t)b * DD) << 11)
                   + ((size_t)(tid >> 3) << 11) + (size_t)(tid & 7) * 16;

  f32x4 oacc[2][8];
#pragma unroll
  for (int qb = 0; qb < 2; ++qb)
#pragma unroll
    for (int dt = 0; dt < 8; ++dt) oacc[qb][dt] = (f32x4)0.0f;
  float mrun[2] = {-1e30f, -1e30f};
  float lrun[2] = {0.0f, 0.0f};   // per-lane partial sums (combined in epilogue)

  f16x8 vreg[16];   // V(t) fragments held in registers across the iteration boundary
  f16x8 pf[2][2];   // P(t) fragments (consumed by PV in iteration t+1)

  // prologue: stage tile 0 into buf 0
  {
    char* sb = sbuf[0];
#pragma unroll
    for (int it = 0; it < 4; ++it)
      gl16(ksrc + it * 4096, sb + it * 4096 + tid * 16);
#pragma unroll
    for (int it = 0; it < 4; ++it)
      gl16(vsrc + it * 65536, sb + 16384 + it * 4096 + tid * 16);
  }
  asm volatile("s_waitcnt vmcnt(0)" ::: "memory");
  __syncthreads();

#pragma unroll 1
  for (int t = 0; t < NTILE; ++t) {
    const char* base = sbuf[t & 1];

    // issue next tile's staging early (lands in the other buffer; V(t-1) lives in regs)
    if (t + 1 < NTILE) {
      char* sb = sbuf[(t + 1) & 1];
      const char* kp = ksrc + (size_t)(t + 1) * 16384;
      const char* vp = vsrc + (size_t)(t + 1) * 128;
#pragma unroll
      for (int it = 0; it < 4; ++it)
        gl16(kp + it * 4096, sb + it * 4096 + tid * 16);
#pragma unroll
      for (int it = 0; it < 4; ++it)
        gl16(vp + it * 65536, sb + 16384 + it * 4096 + tid * 16);
    }

    // ---- S^T = mfma(K, Q): rows kv (lgrp*4+r +16nt), cols q (lrow)
    f32x4 sc[2][4];
#pragma unroll
    for (int qb = 0; qb < 2; ++qb)
#pragma unroll
      for (int nt = 0; nt < 4; ++nt) sc[qb][nt] = (f32x4)0.0f;
#pragma unroll
    for (int nt = 0; nt < 4; ++nt) {
#pragma unroll
      for (int kc = 0; kc < 4; ++kc) {
        const int off = ((kc & 1) ? kO + (kc - 1) * 64 : kE + kc * 64) + nt * 4096;
        f16x8 kf = *(const f16x8*)(base + off);
        sc[0][nt] = __builtin_amdgcn_mfma_f32_16x16x32_f16(kf, qf[0][kc], sc[0][nt], 0, 0, 0);
        sc[1][nt] = __builtin_amdgcn_mfma_f32_16x16x32_f16(kf, qf[1][kc], sc[1][nt], 0, 0, 0);
      }
    }

    // ---- PV(t-1): O^T += mfma(V(t-1), P(t-1)) — independent of QK(t), feeds MFMA pipe
    if (t > 0) {
#pragma unroll
      for (int dt = 0; dt < 8; ++dt) {
        oacc[0][dt] = __builtin_amdgcn_mfma_f32_16x16x32_f16(vreg[dt * 2 + 0], pf[0][0], oacc[0][dt], 0, 0, 0);
        oacc[0][dt] = __builtin_amdgcn_mfma_f32_16x16x32_f16(vreg[dt * 2 + 1], pf[0][1], oacc[0][dt], 0, 0, 0);
        oacc[1][dt] = __builtin_amdgcn_mfma_f32_16x16x32_f16(vreg[dt * 2 + 0], pf[1][0], oacc[1][dt], 0, 0, 0);
        oacc[1][dt] = __builtin_amdgcn_mfma_f32_16x16x32_f16(vreg[dt * 2 + 1], pf[1][1], oacc[1][dt], 0, 0, 0);
      }
    }

    // ---- softmax(t): in-lane max check; cross-lane only on rare trigger
    float mx[2];
#pragma unroll
    for (int qb = 0; qb < 2; ++qb) {
      float a0 = fmaxf(fmaxf(sc[qb][0][0], sc[qb][0][1]), fmaxf(sc[qb][0][2], sc[qb][0][3]));
      float a1 = fmaxf(fmaxf(sc[qb][1][0], sc[qb][1][1]), fmaxf(sc[qb][1][2], sc[qb][1][3]));
      float a2 = fmaxf(fmaxf(sc[qb][2][0], sc[qb][2][1]), fmaxf(sc[qb][2][2], sc[qb][2][3]));
      float a3 = fmaxf(fmaxf(sc[qb][3][0], sc[qb][3][1]), fmaxf(sc[qb][3][2], sc[qb][3][3]));
      mx[qb] = fmaxf(fmaxf(a0, a1), fmaxf(a2, a3));
    }
    bool need = (mx[0] > mrun[0] + RTHR) || (mx[1] > mrun[1] + RTHR);
    if (__any(need)) {
#pragma unroll
      for (int qb = 0; qb < 2; ++qb) {
        float cm = mx[qb];
        cm = fmaxf(cm, __shfl_xor(cm, 16));
        cm = fmaxf(cm, __shfl_xor(cm, 32));
        float mnew = fmaxf(mrun[qb], cm);
        float scale = fexp2((mrun[qb] - mnew) * LOG2E);
        lrun[qb] *= scale;
#pragma unroll
        for (int dt = 0; dt < 8; ++dt) oacc[qb][dt] *= scale;
        mrun[qb] = mnew;
      }
    }

    // ---- P = exp(S - m) in-lane, pack to f16 B-fragments (sigma_V aligned)
#pragma unroll
    for (int qb = 0; qb < 2; ++qb) {
      union { fp16x2 h[8]; f16x8 v[2]; } u;
      float ps = 0.0f;
      const float nml = -mrun[qb] * LOG2E;
#pragma unroll
      for (int nt = 0; nt < 4; ++nt) {
        float p0 = fexp2(fmaf(sc[qb][nt][0], LOG2E, nml));
        float p1 = fexp2(fmaf(sc[qb][nt][1], LOG2E, nml));
        float p2 = fexp2(fmaf(sc[qb][nt][2], LOG2E, nml));
        float p3 = fexp2(fmaf(sc[qb][nt][3], LOG2E, nml));
        ps += (p0 + p1) + (p2 + p3);
        u.h[nt * 2 + 0] = __builtin_amdgcn_cvt_pkrtz(p0, p1);
        u.h[nt * 2 + 1] = __builtin_amdgcn_cvt_pkrtz(p2, p3);
      }
      lrun[qb] += ps;          // per-lane partial; cross-lane sum deferred to epilogue
      pf[qb][0] = u.v[0];
      pf[qb][1] = u.v[1];
    }

    // ---- V(t) LDS -> registers (consumed by PV next iteration)
#pragma unroll
    for (int dt = 0; dt < 8; ++dt) {
      vreg[dt * 2 + 0] = *(const f16x8*)(base + vE + dt * 2048);
      vreg[dt * 2 + 1] = *(const f16x8*)(base + vO + dt * 2048);
    }

    asm volatile("s_waitcnt vmcnt(0)" ::: "memory");
    __syncthreads();
  }

  // ---- drain: PV(NTILE-1)
#pragma unroll
  for (int dt = 0; dt < 8; ++dt) {
    oacc[0][dt] = __builtin_amdgcn_mfma_f32_16x16x32_f16(vreg[dt * 2 + 0], pf[0][0], oacc[0][dt], 0, 0, 0);
    oacc[0][dt] = __builtin_amdgcn_mfma_f32_16x16x32_f16(vreg[dt * 2 + 1], pf[0][1], oacc[0][dt], 0, 0, 0);
    oacc[1][dt] = __builtin_amdgcn_mfma_f32_16x16x32_f16(vreg[dt * 2 + 0], pf[1][0], oacc[1][dt], 0, 0, 0);
    oacc[1][dt] = __builtin_amdgcn_mfma_f32_16x16x32_f16(vreg[dt * 2 + 1], pf[1][1], oacc[1][dt], 0, 0, 0);
  }

  // ---- epilogue: combine per-lane l, normalize, store f32x4
#pragma unroll
  for (int qb = 0; qb < 2; ++qb) {
    float l = lrun[qb];
    l += __shfl_xor(l, 16);
    l += __shfl_xor(l, 32);
    float inv = __builtin_amdgcn_rcpf(l);
    float* op = outp + ((size_t)(b * MM + q0 + qb * 16)) * DD + lgrp * 4;
#pragma unroll
    for (int dt = 0; dt < 8; ++dt) {
      f32x4 v = oacc[qb][dt] * inv;
      *(f32x4*)(op + dt * 16) = v;
    }
  }
}

extern "C" void kernel_launch(void* const* d_in, const int* in_sizes, int n_in,
                              void* d_out, int out_size, void* d_ws, size_t ws_size,
                              hipStream_t stream) {
  const float* A = (const float*)d_in[0];
  const float* B = (const float*)d_in[1];
  float* out = (float*)d_out;
  if (ws_size < 4 * ARR * sizeof(_Float16)) return;  // need 33.6 MB scratch
  _Float16* ws = (_Float16*)d_ws;

  dim3 blk(256, 1, 1);
  dim3 g1(16, 32, 2);
  prep_kernel<<<g1, blk, 0, stream>>>(A, B, ws);
  dim3 g2(512, 1, 1);
  attn_kernel<<<g2, blk, 0, stream>>>(ws, out);
}